// Round 1
// baseline (2201.363 us; speedup 1.0000x reference)
//
#include <hip/hip_runtime.h>
#include <hip/hip_bf16.h>

#define N_NODES 50000
#define N_EDGES 600000
#define DIM 128
#define GROUPS 32
#define EPS 1e-5f

#define NPB 32          // nodes per block in GEMM
#define EPB 8           // edges per block in scatter (256 threads / 32 lanes)

// s[n][d] = t*W[0][d] + b[d] + sum_k xin[n][k] * W[k+1][d]
__global__ __launch_bounds__(256) void gemm_kernel(
    const float* __restrict__ xin, const float* __restrict__ W,
    const float* __restrict__ bias, const float* __restrict__ tptr,
    float* __restrict__ out, int N)
{
    __shared__ float xs[NPB][DIM];
    const int tid = threadIdx.x;
    const int nb = blockIdx.x * NPB;

    // stage x tile: 32 nodes * 128 dims = 1024 float4
    const float4* xin4 = (const float4*)xin;
#pragma unroll
    for (int i = 0; i < 4; ++i) {
        int f4 = tid + i * 256;            // 0..1023
        int nl = f4 >> 5;                  // local node (32 float4 per node)
        int q  = f4 & 31;                  // quad within node
        int node = nb + nl;
        float4 v = make_float4(0.f, 0.f, 0.f, 0.f);
        if (node < N) v = xin4[node * 32 + q];
        *(float4*)&xs[nl][q * 4] = v;
    }
    __syncthreads();

    const int dq   = (tid & 31) * 4;       // dim quad base: 0..124
    const int nloc = (tid >> 5) * 4;       // node base in tile: 0..28

    float4 acc[4];
#pragma unroll
    for (int i = 0; i < 4; ++i) acc[i] = make_float4(0.f, 0.f, 0.f, 0.f);

    for (int k = 0; k < DIM; k += 4) {
        float4 w0 = *(const float4*)&W[(k + 1) * DIM + dq];
        float4 w1 = *(const float4*)&W[(k + 2) * DIM + dq];
        float4 w2 = *(const float4*)&W[(k + 3) * DIM + dq];
        float4 w3 = *(const float4*)&W[(k + 4) * DIM + dq];
#pragma unroll
        for (int i = 0; i < 4; ++i) {
            float4 xv = *(const float4*)&xs[nloc + i][k];
            acc[i].x = fmaf(xv.x, w0.x, fmaf(xv.y, w1.x, fmaf(xv.z, w2.x, fmaf(xv.w, w3.x, acc[i].x))));
            acc[i].y = fmaf(xv.x, w0.y, fmaf(xv.y, w1.y, fmaf(xv.z, w2.y, fmaf(xv.w, w3.y, acc[i].y))));
            acc[i].z = fmaf(xv.x, w0.z, fmaf(xv.y, w1.z, fmaf(xv.z, w2.z, fmaf(xv.w, w3.z, acc[i].z))));
            acc[i].w = fmaf(xv.x, w0.w, fmaf(xv.y, w1.w, fmaf(xv.z, w2.w, fmaf(xv.w, w3.w, acc[i].w))));
        }
    }

    const float tval = *tptr;
    float4 w0r = *(const float4*)&W[dq];        // t-row (row 0 of W)
    float4 bb  = *(const float4*)&bias[dq];
#pragma unroll
    for (int i = 0; i < 4; ++i) {
        int node = nb + nloc + i;
        if (node < N) {
            float4 r;
            r.x = acc[i].x + tval * w0r.x + bb.x;
            r.y = acc[i].y + tval * w0r.y + bb.y;
            r.z = acc[i].z + tval * w0r.z + bb.z;
            r.w = acc[i].w + tval * w0r.w + bb.w;
            *(float4*)&out[node * DIM + dq] = r;
        }
    }
}

// agg[tgt[e]][:] += s[src[e]][:] * edge_w[e]
__global__ __launch_bounds__(256) void scatter_kernel(
    const float* __restrict__ s, const int* __restrict__ src,
    const int* __restrict__ tgt, const float* __restrict__ ew,
    float* __restrict__ agg, int E)
{
    int e = blockIdx.x * EPB + (threadIdx.x >> 5);
    if (e >= E) return;
    int lane = threadIdx.x & 31;
    int sn = src[e];
    int tn = tgt[e];
    float w = ew[e];
    float4 v = *(const float4*)&s[sn * DIM + lane * 4];
    float* dst = &agg[tn * DIM + lane * 4];
    atomicAdd(dst + 0, v.x * w);
    atomicAdd(dst + 1, v.y * w);
    atomicAdd(dst + 2, v.z * w);
    atomicAdd(dst + 3, v.w * w);
}

// out[n][c] = gn(relu(in[n][c])) * gamma[c] + beta[c], groups of 4 channels
__global__ __launch_bounds__(256) void gn_relu_kernel(
    const float* __restrict__ in, float* __restrict__ out,
    const float* __restrict__ gamma, const float* __restrict__ beta, int N)
{
    int idx = blockIdx.x * 256 + threadIdx.x;   // node*32 + g
    if (idx >= N * GROUPS) return;
    int node = idx >> 5;
    int g = idx & 31;
    float4 v = *(const float4*)&in[node * DIM + g * 4];
    v.x = fmaxf(v.x, 0.f);
    v.y = fmaxf(v.y, 0.f);
    v.z = fmaxf(v.z, 0.f);
    v.w = fmaxf(v.w, 0.f);
    float mu = 0.25f * (v.x + v.y + v.z + v.w);
    float dx = v.x - mu, dy = v.y - mu, dz = v.z - mu, dw = v.w - mu;
    float var = 0.25f * (dx * dx + dy * dy + dz * dz + dw * dw);
    float rs = rsqrtf(var + EPS);
    float4 gm = *(const float4*)&gamma[g * 4];
    float4 bt = *(const float4*)&beta[g * 4];
    float4 r;
    r.x = dx * rs * gm.x + bt.x;
    r.y = dy * rs * gm.y + bt.y;
    r.z = dz * rs * gm.z + bt.z;
    r.w = dw * rs * gm.w + bt.w;
    *(float4*)&out[node * DIM + g * 4] = r;
}

extern "C" void kernel_launch(void* const* d_in, const int* in_sizes, int n_in,
                              void* d_out, int out_size, void* d_ws, size_t ws_size,
                              hipStream_t stream) {
    const float* t      = (const float*)d_in[0];
    const float* x      = (const float*)d_in[1];
    const int*   src    = (const int*)d_in[2];
    const int*   tgt    = (const int*)d_in[3];
    const float* edge_w = (const float*)d_in[4];
    const float* W1     = (const float*)d_in[5];
    const float* b1     = (const float*)d_in[6];
    const float* W2     = (const float*)d_in[7];
    const float* b2     = (const float*)d_in[8];
    const float* gamma1 = (const float*)d_in[9];
    const float* beta1  = (const float*)d_in[10];
    const float* gamma2 = (const float*)d_in[11];
    const float* beta2  = (const float*)d_in[12];
    float* out = (float*)d_out;

    const size_t NODE_BYTES = (size_t)N_NODES * DIM * sizeof(float);  // 25.6 MB
    float* s_buf = (float*)d_ws;                                      // ws[0:25.6MB)
    float* h_buf = (float*)((char*)d_ws + NODE_BYTES);                // ws[25.6:51.2MB)

    const int gemm_grid    = (N_NODES + NPB - 1) / NPB;        // 1563
    const int scatter_grid = (N_EDGES + EPB - 1) / EPB;        // 75000
    const int gn_grid      = (N_NODES * GROUPS + 255) / 256;   // 6250

    // ---- layer 1 ----
    gemm_kernel<<<gemm_grid, 256, 0, stream>>>(x, W1, b1, t, s_buf, N_NODES);
    hipMemsetAsync(h_buf, 0, NODE_BYTES, stream);
    scatter_kernel<<<scatter_grid, 256, 0, stream>>>(s_buf, src, tgt, edge_w, h_buf, N_EDGES);
    gn_relu_kernel<<<gn_grid, 256, 0, stream>>>(h_buf, h_buf, gamma1, beta1, N_NODES);

    // ---- layer 2 ----
    gemm_kernel<<<gemm_grid, 256, 0, stream>>>(h_buf, W2, b2, t, s_buf, N_NODES);
    hipMemsetAsync(out, 0, NODE_BYTES, stream);
    scatter_kernel<<<scatter_grid, 256, 0, stream>>>(s_buf, src, tgt, edge_w, out, N_EDGES);
    gn_relu_kernel<<<gn_grid, 256, 0, stream>>>(out, out, gamma2, beta2, N_NODES);
}

// Round 2
// 406.695 us; speedup vs baseline: 5.4128x; 5.4128x over previous
//
#include <hip/hip_runtime.h>
#include <hip/hip_bf16.h>

#define N_NODES 50000
#define N_EDGES 600000
#define DIM 128
#define GROUPS 32
#define EPS 1e-5f

#define NPB 32          // nodes per block in GEMM

// s[n][d] = t*W[0][d] + b[d] + sum_k xin[n][k] * W[k+1][d]
__global__ __launch_bounds__(256) void gemm_kernel(
    const float* __restrict__ xin, const float* __restrict__ W,
    const float* __restrict__ bias, const float* __restrict__ tptr,
    float* __restrict__ out, int N)
{
    __shared__ float xs[NPB][DIM];
    const int tid = threadIdx.x;
    const int nb = blockIdx.x * NPB;

    const float4* xin4 = (const float4*)xin;
#pragma unroll
    for (int i = 0; i < 4; ++i) {
        int f4 = tid + i * 256;            // 0..1023
        int nl = f4 >> 5;
        int q  = f4 & 31;
        int node = nb + nl;
        float4 v = make_float4(0.f, 0.f, 0.f, 0.f);
        if (node < N) v = xin4[node * 32 + q];
        *(float4*)&xs[nl][q * 4] = v;
    }
    __syncthreads();

    const int dq   = (tid & 31) * 4;
    const int nloc = (tid >> 5) * 4;

    float4 acc[4];
#pragma unroll
    for (int i = 0; i < 4; ++i) acc[i] = make_float4(0.f, 0.f, 0.f, 0.f);

    for (int k = 0; k < DIM; k += 4) {
        float4 w0 = *(const float4*)&W[(k + 1) * DIM + dq];
        float4 w1 = *(const float4*)&W[(k + 2) * DIM + dq];
        float4 w2 = *(const float4*)&W[(k + 3) * DIM + dq];
        float4 w3 = *(const float4*)&W[(k + 4) * DIM + dq];
#pragma unroll
        for (int i = 0; i < 4; ++i) {
            float4 xv = *(const float4*)&xs[nloc + i][k];
            acc[i].x = fmaf(xv.x, w0.x, fmaf(xv.y, w1.x, fmaf(xv.z, w2.x, fmaf(xv.w, w3.x, acc[i].x))));
            acc[i].y = fmaf(xv.x, w0.y, fmaf(xv.y, w1.y, fmaf(xv.z, w2.y, fmaf(xv.w, w3.y, acc[i].y))));
            acc[i].z = fmaf(xv.x, w0.z, fmaf(xv.y, w1.z, fmaf(xv.z, w2.z, fmaf(xv.w, w3.z, acc[i].z))));
            acc[i].w = fmaf(xv.x, w0.w, fmaf(xv.y, w1.w, fmaf(xv.z, w2.w, fmaf(xv.w, w3.w, acc[i].w))));
        }
    }

    const float tval = *tptr;
    float4 w0r = *(const float4*)&W[dq];        // t-row (row 0 of W)
    float4 bb  = *(const float4*)&bias[dq];
#pragma unroll
    for (int i = 0; i < 4; ++i) {
        int node = nb + nloc + i;
        if (node < N) {
            float4 r;
            r.x = acc[i].x + tval * w0r.x + bb.x;
            r.y = acc[i].y + tval * w0r.y + bb.y;
            r.z = acc[i].z + tval * w0r.z + bb.z;
            r.w = acc[i].w + tval * w0r.w + bb.w;
            *(float4*)&out[node * DIM + dq] = r;
        }
    }
}

// ---- CSR build ----
__global__ __launch_bounds__(256) void hist_kernel(
    const int* __restrict__ tgt, int* __restrict__ counts, int E)
{
    int e = blockIdx.x * 256 + threadIdx.x;
    if (e < E) atomicAdd(&counts[tgt[e]], 1);
}

// single-block exclusive scan of counts[0..N) -> rowptr[0..N]
__global__ __launch_bounds__(256) void scan_kernel(
    const int* __restrict__ counts, int* __restrict__ rowptr, int N)
{
    __shared__ int sums[256];
    const int tid = threadIdx.x;
    const int CHUNK = (N + 255) / 256;
    int beg = tid * CHUNK;
    int end = min(beg + CHUNK, N);
    int s = 0;
    for (int i = beg; i < end; ++i) s += counts[i];
    sums[tid] = s;
    __syncthreads();
    for (int off = 1; off < 256; off <<= 1) {
        int other = (tid >= off) ? sums[tid - off] : 0;
        __syncthreads();
        sums[tid] += other;
        __syncthreads();
    }
    int run = sums[tid] - s;   // exclusive prefix of my chunk
    for (int i = beg; i < end; ++i) {
        rowptr[i] = run;
        run += counts[i];
    }
    if (tid == 255) rowptr[N] = sums[255];
}

// edges[pos] = (src, w) bucketed by tgt
__global__ __launch_bounds__(256) void place_kernel(
    const int* __restrict__ src, const int* __restrict__ tgt,
    const float* __restrict__ ew, const int* __restrict__ rowptr,
    int* __restrict__ cursor, int2* __restrict__ edges, int E)
{
    int e = blockIdx.x * 256 + threadIdx.x;
    if (e >= E) return;
    int t = tgt[e];
    int pos = rowptr[t] + atomicAdd(&cursor[t], 1);
    edges[pos] = make_int2(src[e], __float_as_int(ew[e]));
}

// per node: acc = sum_{j in row} s[src_j]*w_j ; out = GN(relu(acc))*gamma+beta
// 32 lanes per node (lane = one 4-channel group = one GN group)
__global__ __launch_bounds__(256) void gather_gn_kernel(
    const float* __restrict__ s, const int* __restrict__ rowptr,
    const int2* __restrict__ edges,
    const float* __restrict__ gamma, const float* __restrict__ beta,
    float* __restrict__ out, int N)
{
    int node = blockIdx.x * 8 + (threadIdx.x >> 5);
    if (node >= N) return;
    int lane = threadIdx.x & 31;

    int beg = rowptr[node];
    int end = rowptr[node + 1];

    float4 acc = make_float4(0.f, 0.f, 0.f, 0.f);
    int j = beg;
    for (; j + 1 < end; j += 2) {
        int2 r0 = edges[j];
        int2 r1 = edges[j + 1];
        float4 v0 = *(const float4*)&s[(size_t)r0.x * DIM + lane * 4];
        float4 v1 = *(const float4*)&s[(size_t)r1.x * DIM + lane * 4];
        float w0 = __int_as_float(r0.y);
        float w1 = __int_as_float(r1.y);
        acc.x += v0.x * w0 + v1.x * w1;
        acc.y += v0.y * w0 + v1.y * w1;
        acc.z += v0.z * w0 + v1.z * w1;
        acc.w += v0.w * w0 + v1.w * w1;
    }
    if (j < end) {
        int2 r0 = edges[j];
        float4 v0 = *(const float4*)&s[(size_t)r0.x * DIM + lane * 4];
        float w0 = __int_as_float(r0.y);
        acc.x += v0.x * w0;
        acc.y += v0.y * w0;
        acc.z += v0.z * w0;
        acc.w += v0.w * w0;
    }

    // relu
    acc.x = fmaxf(acc.x, 0.f);
    acc.y = fmaxf(acc.y, 0.f);
    acc.z = fmaxf(acc.z, 0.f);
    acc.w = fmaxf(acc.w, 0.f);
    // group norm over the 4 channels this lane owns
    float mu = 0.25f * (acc.x + acc.y + acc.z + acc.w);
    float dx = acc.x - mu, dy = acc.y - mu, dz = acc.z - mu, dw = acc.w - mu;
    float var = 0.25f * (dx * dx + dy * dy + dz * dz + dw * dw);
    float rs = rsqrtf(var + EPS);
    float4 gm = *(const float4*)&gamma[lane * 4];
    float4 bt = *(const float4*)&beta[lane * 4];
    float4 r;
    r.x = dx * rs * gm.x + bt.x;
    r.y = dy * rs * gm.y + bt.y;
    r.z = dz * rs * gm.z + bt.z;
    r.w = dw * rs * gm.w + bt.w;
    *(float4*)&out[(size_t)node * DIM + lane * 4] = r;
}

extern "C" void kernel_launch(void* const* d_in, const int* in_sizes, int n_in,
                              void* d_out, int out_size, void* d_ws, size_t ws_size,
                              hipStream_t stream) {
    const float* t      = (const float*)d_in[0];
    const float* x      = (const float*)d_in[1];
    const int*   src    = (const int*)d_in[2];
    const int*   tgt    = (const int*)d_in[3];
    const float* edge_w = (const float*)d_in[4];
    const float* W1     = (const float*)d_in[5];
    const float* b1     = (const float*)d_in[6];
    const float* W2     = (const float*)d_in[7];
    const float* b2     = (const float*)d_in[8];
    const float* gamma1 = (const float*)d_in[9];
    const float* beta1  = (const float*)d_in[10];
    const float* gamma2 = (const float*)d_in[11];
    const float* beta2  = (const float*)d_in[12];
    float* out = (float*)d_out;

    const size_t NODE_BYTES = (size_t)N_NODES * DIM * sizeof(float);  // 25.6 MB
    char* ws = (char*)d_ws;
    size_t off = 0;
    float* s_buf  = (float*)(ws + off); off += NODE_BYTES;                 // 25.6 MB
    int*   rowptr = (int*)(ws + off);   off += ((size_t)N_NODES + 1) * 4;  // 200 KB
    off = (off + 255) & ~(size_t)255;
    int*   cursor = (int*)(ws + off);   off += (size_t)N_NODES * 4;        // 200 KB
    off = (off + 255) & ~(size_t)255;
    int2*  edges  = (int2*)(ws + off);  off += (size_t)N_EDGES * 8;        // 4.8 MB

    const int gemm_grid   = (N_NODES + NPB - 1) / NPB;     // 1563
    const int edge_grid   = (N_EDGES + 255) / 256;         // 2344
    const int gather_grid = (N_NODES + 7) / 8;             // 6250

    // ---- CSR build (shared by both layers) ----
    hipMemsetAsync(cursor, 0, (size_t)N_NODES * 4, stream);
    hist_kernel<<<edge_grid, 256, 0, stream>>>(tgt, cursor, N_EDGES);      // cursor = counts
    scan_kernel<<<1, 256, 0, stream>>>(cursor, rowptr, N_NODES);
    hipMemsetAsync(cursor, 0, (size_t)N_NODES * 4, stream);
    place_kernel<<<edge_grid, 256, 0, stream>>>(src, tgt, edge_w, rowptr, cursor, edges, N_EDGES);

    // ---- layer 1 ----  (h lives in d_out; gemm2 consumes it before gather2 overwrites)
    gemm_kernel<<<gemm_grid, 256, 0, stream>>>(x, W1, b1, t, s_buf, N_NODES);
    gather_gn_kernel<<<gather_grid, 256, 0, stream>>>(s_buf, rowptr, edges, gamma1, beta1, out, N_NODES);

    // ---- layer 2 ----
    gemm_kernel<<<gemm_grid, 256, 0, stream>>>(out, W2, b2, t, s_buf, N_NODES);
    gather_gn_kernel<<<gather_grid, 256, 0, stream>>>(s_buf, rowptr, edges, gamma2, beta2, out, N_NODES);
}

// Round 3
// 322.955 us; speedup vs baseline: 6.8163x; 1.2593x over previous
//
#include <hip/hip_runtime.h>
#include <hip/hip_bf16.h>

#define N_NODES 50000
#define N_EDGES 600000
#define DIM 128
#define GROUPS 32
#define EPS 1e-5f

#define NPB 32              // nodes per block in GEMM
#define SCAN_CHUNK 1024     // counts per block in scan passes
#define SCAN_NB ((N_NODES + SCAN_CHUNK - 1) / SCAN_CHUNK)   // 49

// s[n][d] = t*W[0][d] + b[d] + sum_k xin[n][k] * W[k+1][d]
__global__ __launch_bounds__(256) void gemm_kernel(
    const float* __restrict__ xin, const float* __restrict__ W,
    const float* __restrict__ bias, const float* __restrict__ tptr,
    float* __restrict__ out, int N)
{
    __shared__ float xs[NPB][DIM];
    const int tid = threadIdx.x;
    const int nb = blockIdx.x * NPB;

    const float4* xin4 = (const float4*)xin;
#pragma unroll
    for (int i = 0; i < 4; ++i) {
        int f4 = tid + i * 256;            // 0..1023
        int nl = f4 >> 5;
        int q  = f4 & 31;
        int node = nb + nl;
        float4 v = make_float4(0.f, 0.f, 0.f, 0.f);
        if (node < N) v = xin4[node * 32 + q];
        *(float4*)&xs[nl][q * 4] = v;
    }
    __syncthreads();

    const int dq   = (tid & 31) * 4;
    const int nloc = (tid >> 5) * 4;

    float4 acc[4];
#pragma unroll
    for (int i = 0; i < 4; ++i) acc[i] = make_float4(0.f, 0.f, 0.f, 0.f);

    for (int k = 0; k < DIM; k += 4) {
        float4 w0 = *(const float4*)&W[(k + 1) * DIM + dq];
        float4 w1 = *(const float4*)&W[(k + 2) * DIM + dq];
        float4 w2 = *(const float4*)&W[(k + 3) * DIM + dq];
        float4 w3 = *(const float4*)&W[(k + 4) * DIM + dq];
#pragma unroll
        for (int i = 0; i < 4; ++i) {
            float4 xv = *(const float4*)&xs[nloc + i][k];
            acc[i].x = fmaf(xv.x, w0.x, fmaf(xv.y, w1.x, fmaf(xv.z, w2.x, fmaf(xv.w, w3.x, acc[i].x))));
            acc[i].y = fmaf(xv.x, w0.y, fmaf(xv.y, w1.y, fmaf(xv.z, w2.y, fmaf(xv.w, w3.y, acc[i].y))));
            acc[i].z = fmaf(xv.x, w0.z, fmaf(xv.y, w1.z, fmaf(xv.z, w2.z, fmaf(xv.w, w3.z, acc[i].z))));
            acc[i].w = fmaf(xv.x, w0.w, fmaf(xv.y, w1.w, fmaf(xv.z, w2.w, fmaf(xv.w, w3.w, acc[i].w))));
        }
    }

    const float tval = *tptr;
    float4 w0r = *(const float4*)&W[dq];        // t-row (row 0 of W)
    float4 bb  = *(const float4*)&bias[dq];
#pragma unroll
    for (int i = 0; i < 4; ++i) {
        int node = nb + nloc + i;
        if (node < N) {
            float4 r;
            r.x = acc[i].x + tval * w0r.x + bb.x;
            r.y = acc[i].y + tval * w0r.y + bb.y;
            r.z = acc[i].z + tval * w0r.z + bb.z;
            r.w = acc[i].w + tval * w0r.w + bb.w;
            *(float4*)&out[node * DIM + dq] = r;
        }
    }
}

// ---- CSR build ----
__global__ __launch_bounds__(256) void hist_kernel(
    const int* __restrict__ tgt, int* __restrict__ counts, int E)
{
    int e = blockIdx.x * 256 + threadIdx.x;
    if (e < E) atomicAdd(&counts[tgt[e]], 1);
}

// pass 1: bsum[b] = sum of counts[b*1024 .. b*1024+1023]
__global__ __launch_bounds__(256) void scan_pass1(
    const int* __restrict__ counts, int* __restrict__ bsum, int N)
{
    __shared__ int sh[256];
    const int tid = threadIdx.x;
    const int n4 = N / 4;                      // 12500, N divisible by 4
    int idx4 = blockIdx.x * 256 + tid;
    int4 c = make_int4(0, 0, 0, 0);
    if (idx4 < n4) c = ((const int4*)counts)[idx4];
    sh[tid] = c.x + c.y + c.z + c.w;
    __syncthreads();
#pragma unroll
    for (int off = 128; off > 0; off >>= 1) {
        if (tid < off) sh[tid] += sh[tid + off];
        __syncthreads();
    }
    if (tid == 0) bsum[blockIdx.x] = sh[0];
}

// pass 2: exclusive scan of bsum[0..nb) in one wave (nb <= 64)
__global__ __launch_bounds__(64) void scan_bsum(int* __restrict__ bsum, int nb)
{
    int lane = threadIdx.x;
    int v = (lane < nb) ? bsum[lane] : 0;
    int incl = v;
#pragma unroll
    for (int off = 1; off < 64; off <<= 1) {
        int u = __shfl_up(incl, off);
        if (lane >= off) incl += u;
    }
    if (lane < nb) bsum[lane] = incl - v;      // exclusive
}

// pass 3: rowptr = exclusive scan of counts, using bsum offsets; also rowptr[N]
__global__ __launch_bounds__(256) void scan_pass3(
    const int* __restrict__ counts, const int* __restrict__ bsum,
    int* __restrict__ rowptr, int N)
{
    __shared__ int sh[256];
    const int tid = threadIdx.x;
    const int n4 = N / 4;
    int idx4 = blockIdx.x * 256 + tid;
    int4 c = make_int4(0, 0, 0, 0);
    if (idx4 < n4) c = ((const int4*)counts)[idx4];
    int tsum = c.x + c.y + c.z + c.w;
    sh[tid] = tsum;
    __syncthreads();
#pragma unroll
    for (int off = 1; off < 256; off <<= 1) {
        int v = (tid >= off) ? sh[tid - off] : 0;
        __syncthreads();
        sh[tid] += v;
        __syncthreads();
    }
    int base = bsum[blockIdx.x] + sh[tid] - tsum;   // exclusive prefix for my 4
    if (idx4 < n4) {
        int4 r;
        r.x = base;
        r.y = base + c.x;
        r.z = r.y + c.y;
        r.w = r.z + c.z;
        ((int4*)rowptr)[idx4] = r;
        if (idx4 == n4 - 1) rowptr[N] = r.w + c.w;
    }
}

// edges[pos] = (src, w) bucketed by tgt
__global__ __launch_bounds__(256) void place_kernel(
    const int* __restrict__ src, const int* __restrict__ tgt,
    const float* __restrict__ ew, const int* __restrict__ rowptr,
    int* __restrict__ cursor, int2* __restrict__ edges, int E)
{
    int e = blockIdx.x * 256 + threadIdx.x;
    if (e >= E) return;
    int t = tgt[e];
    int pos = rowptr[t] + atomicAdd(&cursor[t], 1);
    edges[pos] = make_int2(src[e], __float_as_int(ew[e]));
}

// per node: acc = sum_{j in row} s[src_j]*w_j ; out = GN(relu(acc))*gamma+beta
// 32 lanes per node (lane = one 4-channel group = one GN group)
__global__ __launch_bounds__(256) void gather_gn_kernel(
    const float* __restrict__ s, const int* __restrict__ rowptr,
    const int2* __restrict__ edges,
    const float* __restrict__ gamma, const float* __restrict__ beta,
    float* __restrict__ out, int N)
{
    int node = blockIdx.x * 8 + (threadIdx.x >> 5);
    if (node >= N) return;
    int lane = threadIdx.x & 31;

    int beg = rowptr[node];
    int end = rowptr[node + 1];

    float4 acc = make_float4(0.f, 0.f, 0.f, 0.f);
    int j = beg;
    for (; j + 1 < end; j += 2) {
        int2 r0 = edges[j];
        int2 r1 = edges[j + 1];
        float4 v0 = *(const float4*)&s[(size_t)r0.x * DIM + lane * 4];
        float4 v1 = *(const float4*)&s[(size_t)r1.x * DIM + lane * 4];
        float w0 = __int_as_float(r0.y);
        float w1 = __int_as_float(r1.y);
        acc.x += v0.x * w0 + v1.x * w1;
        acc.y += v0.y * w0 + v1.y * w1;
        acc.z += v0.z * w0 + v1.z * w1;
        acc.w += v0.w * w0 + v1.w * w1;
    }
    if (j < end) {
        int2 r0 = edges[j];
        float4 v0 = *(const float4*)&s[(size_t)r0.x * DIM + lane * 4];
        float w0 = __int_as_float(r0.y);
        acc.x += v0.x * w0;
        acc.y += v0.y * w0;
        acc.z += v0.z * w0;
        acc.w += v0.w * w0;
    }

    // relu
    acc.x = fmaxf(acc.x, 0.f);
    acc.y = fmaxf(acc.y, 0.f);
    acc.z = fmaxf(acc.z, 0.f);
    acc.w = fmaxf(acc.w, 0.f);
    // group norm over the 4 channels this lane owns
    float mu = 0.25f * (acc.x + acc.y + acc.z + acc.w);
    float dx = acc.x - mu, dy = acc.y - mu, dz = acc.z - mu, dw = acc.w - mu;
    float var = 0.25f * (dx * dx + dy * dy + dz * dz + dw * dw);
    float rs = rsqrtf(var + EPS);
    float4 gm = *(const float4*)&gamma[lane * 4];
    float4 bt = *(const float4*)&beta[lane * 4];
    float4 r;
    r.x = dx * rs * gm.x + bt.x;
    r.y = dy * rs * gm.y + bt.y;
    r.z = dz * rs * gm.z + bt.z;
    r.w = dw * rs * gm.w + bt.w;
    *(float4*)&out[(size_t)node * DIM + lane * 4] = r;
}

extern "C" void kernel_launch(void* const* d_in, const int* in_sizes, int n_in,
                              void* d_out, int out_size, void* d_ws, size_t ws_size,
                              hipStream_t stream) {
    const float* t      = (const float*)d_in[0];
    const float* x      = (const float*)d_in[1];
    const int*   src    = (const int*)d_in[2];
    const int*   tgt    = (const int*)d_in[3];
    const float* edge_w = (const float*)d_in[4];
    const float* W1     = (const float*)d_in[5];
    const float* b1     = (const float*)d_in[6];
    const float* W2     = (const float*)d_in[7];
    const float* b2     = (const float*)d_in[8];
    const float* gamma1 = (const float*)d_in[9];
    const float* beta1  = (const float*)d_in[10];
    const float* gamma2 = (const float*)d_in[11];
    const float* beta2  = (const float*)d_in[12];
    float* out = (float*)d_out;

    const size_t NODE_BYTES = (size_t)N_NODES * DIM * sizeof(float);  // 25.6 MB
    char* ws = (char*)d_ws;
    size_t off = 0;
    float* s_buf  = (float*)(ws + off); off += NODE_BYTES;                 // 25.6 MB
    int*   rowptr = (int*)(ws + off);   off += ((size_t)N_NODES + 4) * 4;
    off = (off + 255) & ~(size_t)255;
    int*   cursor = (int*)(ws + off);   off += (size_t)N_NODES * 4;
    off = (off + 255) & ~(size_t)255;
    int*   bsum   = (int*)(ws + off);   off += 64 * 4;
    off = (off + 255) & ~(size_t)255;
    int2*  edges  = (int2*)(ws + off);  off += (size_t)N_EDGES * 8;        // 4.8 MB

    const int gemm_grid   = (N_NODES + NPB - 1) / NPB;     // 1563
    const int edge_grid   = (N_EDGES + 255) / 256;         // 2344
    const int gather_grid = (N_NODES + 7) / 8;             // 6250

    // ---- CSR build (shared by both layers) ----
    hipMemsetAsync(cursor, 0, (size_t)N_NODES * 4, stream);
    hist_kernel<<<edge_grid, 256, 0, stream>>>(tgt, cursor, N_EDGES);      // cursor = counts
    scan_pass1<<<SCAN_NB, 256, 0, stream>>>(cursor, bsum, N_NODES);
    scan_bsum<<<1, 64, 0, stream>>>(bsum, SCAN_NB);
    scan_pass3<<<SCAN_NB, 256, 0, stream>>>(cursor, bsum, rowptr, N_NODES);
    hipMemsetAsync(cursor, 0, (size_t)N_NODES * 4, stream);
    place_kernel<<<edge_grid, 256, 0, stream>>>(src, tgt, edge_w, rowptr, cursor, edges, N_EDGES);

    // ---- layer 1 ----  (h lives in d_out; gemm2 consumes it before gather2 overwrites)
    gemm_kernel<<<gemm_grid, 256, 0, stream>>>(x, W1, b1, t, s_buf, N_NODES);
    gather_gn_kernel<<<gather_grid, 256, 0, stream>>>(s_buf, rowptr, edges, gamma1, beta1, out, N_NODES);

    // ---- layer 2 ----
    gemm_kernel<<<gemm_grid, 256, 0, stream>>>(out, W2, b2, t, s_buf, N_NODES);
    gather_gn_kernel<<<gather_grid, 256, 0, stream>>>(s_buf, rowptr, edges, gamma2, beta2, out, N_NODES);
}

// Round 5
// 309.260 us; speedup vs baseline: 7.1182x; 1.0443x over previous
//
#include <hip/hip_runtime.h>
#include <hip/hip_bf16.h>

#define N_NODES 50000
#define N_EDGES 600000
#define DIM 128
#define GROUPS 32
#define EPS 1e-5f

#define NPB 64              // nodes per block in GEMM
#define SCAN_CHUNK 1024     // counts per block in scan passes
#define SCAN_NB ((N_NODES + SCAN_CHUNK - 1) / SCAN_CHUNK)   // 49

// s[n][d] = t*W[0][d] + b[d] + sum_k xin[n][k] * W[k+1][d]
__global__ __launch_bounds__(256) void gemm_kernel(
    const float* __restrict__ xin, const float* __restrict__ W,
    const float* __restrict__ bias, const float* __restrict__ tptr,
    float* __restrict__ out, int N)
{
    __shared__ float xs[NPB][DIM];     // 32 KB
    const int tid = threadIdx.x;
    const int nb = blockIdx.x * NPB;

    // stage x tile: 64 nodes * 32 float4 = 2048 float4, 8 per thread
    const float4* xin4 = (const float4*)xin;
#pragma unroll
    for (int i = 0; i < 8; ++i) {
        int f4 = tid + i * 256;            // 0..2047
        int nl = f4 >> 5;                  // local node
        int q  = f4 & 31;                  // float4 within node
        int node = nb + nl;
        float4 v = make_float4(0.f, 0.f, 0.f, 0.f);
        if (node < N) v = xin4[(size_t)node * 32 + q];
        *(float4*)&xs[nl][q * 4] = v;
    }
    __syncthreads();

    const int dq   = (tid & 31) * 4;       // dim quad base 0..124
    const int nloc = (tid >> 5) * 8;       // node base in tile 0..56

    float4 acc[8];
#pragma unroll
    for (int i = 0; i < 8; ++i) acc[i] = make_float4(0.f, 0.f, 0.f, 0.f);

    for (int k = 0; k < DIM; k += 4) {
        float4 w0 = *(const float4*)&W[(k + 1) * DIM + dq];
        float4 w1 = *(const float4*)&W[(k + 2) * DIM + dq];
        float4 w2 = *(const float4*)&W[(k + 3) * DIM + dq];
        float4 w3 = *(const float4*)&W[(k + 4) * DIM + dq];
#pragma unroll
        for (int i = 0; i < 8; ++i) {
            float4 xv = *(const float4*)&xs[nloc + i][k];
            acc[i].x = fmaf(xv.x, w0.x, fmaf(xv.y, w1.x, fmaf(xv.z, w2.x, fmaf(xv.w, w3.x, acc[i].x))));
            acc[i].y = fmaf(xv.x, w0.y, fmaf(xv.y, w1.y, fmaf(xv.z, w2.y, fmaf(xv.w, w3.y, acc[i].y))));
            acc[i].z = fmaf(xv.x, w0.z, fmaf(xv.y, w1.z, fmaf(xv.z, w2.z, fmaf(xv.w, w3.z, acc[i].z))));
            acc[i].w = fmaf(xv.x, w0.w, fmaf(xv.y, w1.w, fmaf(xv.z, w2.w, fmaf(xv.w, w3.w, acc[i].w))));
        }
    }

    const float tval = *tptr;
    float4 w0r = *(const float4*)&W[dq];        // t-row (row 0 of W)
    float4 bb  = *(const float4*)&bias[dq];
#pragma unroll
    for (int i = 0; i < 8; ++i) {
        int node = nb + nloc + i;
        if (node < N) {
            float4 r;
            r.x = acc[i].x + tval * w0r.x + bb.x;
            r.y = acc[i].y + tval * w0r.y + bb.y;
            r.z = acc[i].z + tval * w0r.z + bb.z;
            r.w = acc[i].w + tval * w0r.w + bb.w;
            *(float4*)&out[(size_t)node * DIM + dq] = r;
        }
    }
}

// ---- CSR build ----
__global__ __launch_bounds__(256) void hist_kernel(
    const int* __restrict__ tgt, int* __restrict__ counts, int E)
{
    int e = blockIdx.x * 256 + threadIdx.x;
    if (e < E) atomicAdd(&counts[tgt[e]], 1);
}

// pass 1: bsum[b] = sum of counts[b*1024 .. b*1024+1023]
__global__ __launch_bounds__(256) void scan_pass1(
    const int* __restrict__ counts, int* __restrict__ bsum, int N)
{
    __shared__ int sh[256];
    const int tid = threadIdx.x;
    const int n4 = N / 4;
    int idx4 = blockIdx.x * 256 + tid;
    int4 c = make_int4(0, 0, 0, 0);
    if (idx4 < n4) c = ((const int4*)counts)[idx4];
    sh[tid] = c.x + c.y + c.z + c.w;
    __syncthreads();
#pragma unroll
    for (int off = 128; off > 0; off >>= 1) {
        if (tid < off) sh[tid] += sh[tid + off];
        __syncthreads();
    }
    if (tid == 0) bsum[blockIdx.x] = sh[0];
}

// pass 2: exclusive scan of bsum[0..nb) in one wave (nb <= 64)
__global__ __launch_bounds__(64) void scan_bsum(int* __restrict__ bsum, int nb)
{
    int lane = threadIdx.x;
    int v = (lane < nb) ? bsum[lane] : 0;
    int incl = v;
#pragma unroll
    for (int off = 1; off < 64; off <<= 1) {
        int u = __shfl_up(incl, off);
        if (lane >= off) incl += u;
    }
    if (lane < nb) bsum[lane] = incl - v;      // exclusive
}

// pass 3: rowptr = exclusive scan of counts, using bsum offsets; also rowptr[N]
__global__ __launch_bounds__(256) void scan_pass3(
    const int* __restrict__ counts, const int* __restrict__ bsum,
    int* __restrict__ rowptr, int N)
{
    __shared__ int sh[256];
    const int tid = threadIdx.x;
    const int n4 = N / 4;
    int idx4 = blockIdx.x * 256 + tid;
    int4 c = make_int4(0, 0, 0, 0);
    if (idx4 < n4) c = ((const int4*)counts)[idx4];
    int tsum = c.x + c.y + c.z + c.w;
    sh[tid] = tsum;
    __syncthreads();
#pragma unroll
    for (int off = 1; off < 256; off <<= 1) {
        int v = (tid >= off) ? sh[tid - off] : 0;
        __syncthreads();
        sh[tid] += v;
        __syncthreads();
    }
    int base = bsum[blockIdx.x] + sh[tid] - tsum;   // exclusive prefix for my 4
    if (idx4 < n4) {
        int4 r;
        r.x = base;
        r.y = base + c.x;
        r.z = r.y + c.y;
        r.w = r.z + c.z;
        ((int4*)rowptr)[idx4] = r;
        if (idx4 == n4 - 1) rowptr[N] = r.w + c.w;
    }
}

// eid[pos] = src, bucketed by tgt. cursor holds counts on entry, 0 on exit.
__global__ __launch_bounds__(256) void place_kernel(
    const int* __restrict__ src, const int* __restrict__ tgt,
    const int* __restrict__ rowptr,
    int* __restrict__ cursor, int* __restrict__ eid, int E)
{
    int e = blockIdx.x * 256 + threadIdx.x;
    if (e >= E) return;
    int t = tgt[e];
    int idx = atomicSub(&cursor[t], 1) - 1;    // slot within row
    eid[rowptr[t] + idx] = src[e];
}

// One 64-lane wave per node: half = lane>>5 picks edge parity, quad = lane&31
// picks the float4 of the row. acc = (1/deg) * sum s[src_j]; out = GN(relu(acc)).
__global__ __launch_bounds__(256) void gather_gn_kernel(
    const float4* __restrict__ s4, const int* __restrict__ rowptr,
    const int* __restrict__ eid,
    const float* __restrict__ gamma, const float* __restrict__ beta,
    float* __restrict__ out, int N)
{
    int node = blockIdx.x * 4 + (threadIdx.x >> 6);
    if (node >= N) return;
    int lane = threadIdx.x & 63;
    int half = lane >> 5;
    int quad = lane & 31;

    int beg = rowptr[node];
    int end = rowptr[node + 1];

    float4 acc = make_float4(0.f, 0.f, 0.f, 0.f);
    int j = beg + half;
    // 4 edges per iteration (2 per half-wave)
    for (; j + 2 < end; j += 4) {
        int i0 = eid[j];
        int i1 = eid[j + 2];
        float4 v0 = s4[(size_t)i0 * 32 + quad];
        float4 v1 = s4[(size_t)i1 * 32 + quad];
        acc.x += v0.x + v1.x;
        acc.y += v0.y + v1.y;
        acc.z += v0.z + v1.z;
        acc.w += v0.w + v1.w;
    }
    for (; j < end; j += 2) {
        float4 v0 = s4[(size_t)eid[j] * 32 + quad];
        acc.x += v0.x;
        acc.y += v0.y;
        acc.z += v0.z;
        acc.w += v0.w;
    }

    // combine the two halves: lane q gets half0[q] + half1[q]
    acc.x += __shfl_xor(acc.x, 32);
    acc.y += __shfl_xor(acc.y, 32);
    acc.z += __shfl_xor(acc.z, 32);
    acc.w += __shfl_xor(acc.w, 32);

    if (half == 0) {
        int deg = end - beg;
        float inv = (deg > 0) ? (1.0f / (float)deg) : 0.0f;
        acc.x = fmaxf(acc.x * inv, 0.f);
        acc.y = fmaxf(acc.y * inv, 0.f);
        acc.z = fmaxf(acc.z * inv, 0.f);
        acc.w = fmaxf(acc.w * inv, 0.f);

        float mu = 0.25f * (acc.x + acc.y + acc.z + acc.w);
        float dx = acc.x - mu, dy = acc.y - mu, dz = acc.z - mu, dw = acc.w - mu;
        float var = 0.25f * (dx * dx + dy * dy + dz * dz + dw * dw);
        float rs = rsqrtf(var + EPS);
        float4 gm = *(const float4*)&gamma[quad * 4];
        float4 bt = *(const float4*)&beta[quad * 4];
        float4 r;
        r.x = dx * rs * gm.x + bt.x;
        r.y = dy * rs * gm.y + bt.y;
        r.z = dz * rs * gm.z + bt.z;
        r.w = dw * rs * gm.w + bt.w;
        *(float4*)&out[(size_t)node * DIM + quad * 4] = r;
    }
}

extern "C" void kernel_launch(void* const* d_in, const int* in_sizes, int n_in,
                              void* d_out, int out_size, void* d_ws, size_t ws_size,
                              hipStream_t stream) {
    const float* t      = (const float*)d_in[0];
    const float* x      = (const float*)d_in[1];
    const int*   src    = (const int*)d_in[2];
    const int*   tgt    = (const int*)d_in[3];
    const float* W1     = (const float*)d_in[5];
    const float* b1     = (const float*)d_in[6];
    const float* W2     = (const float*)d_in[7];
    const float* b2     = (const float*)d_in[8];
    const float* gamma1 = (const float*)d_in[9];
    const float* beta1  = (const float*)d_in[10];
    const float* gamma2 = (const float*)d_in[11];
    const float* beta2  = (const float*)d_in[12];
    float* out = (float*)d_out;

    const size_t NODE_BYTES = (size_t)N_NODES * DIM * sizeof(float);  // 25.6 MB
    char* ws = (char*)d_ws;
    size_t off = 0;
    float* s_buf  = (float*)(ws + off); off += NODE_BYTES;                 // 25.6 MB
    int*   rowptr = (int*)(ws + off);   off += ((size_t)N_NODES + 4) * 4;
    off = (off + 255) & ~(size_t)255;
    int*   cursor = (int*)(ws + off);   off += (size_t)N_NODES * 4;
    off = (off + 255) & ~(size_t)255;
    int*   bsum   = (int*)(ws + off);   off += 64 * 4;
    off = (off + 255) & ~(size_t)255;
    int*   eid    = (int*)(ws + off);   off += (size_t)N_EDGES * 4;        // 2.4 MB

    const int gemm_grid   = (N_NODES + NPB - 1) / NPB;     // 782
    const int edge_grid   = (N_EDGES + 255) / 256;         // 2344
    const int gather_grid = (N_NODES + 3) / 4;             // 12500

    // ---- CSR build (shared by both layers) ----
    hipMemsetAsync(cursor, 0, (size_t)N_NODES * 4, stream);
    hist_kernel<<<edge_grid, 256, 0, stream>>>(tgt, cursor, N_EDGES);      // cursor = counts
    scan_pass1<<<SCAN_NB, 256, 0, stream>>>(cursor, bsum, N_NODES);
    scan_bsum<<<1, 64, 0, stream>>>(bsum, SCAN_NB);
    scan_pass3<<<SCAN_NB, 256, 0, stream>>>(cursor, bsum, rowptr, N_NODES);
    place_kernel<<<edge_grid, 256, 0, stream>>>(src, tgt, rowptr, cursor, eid, N_EDGES);

    // ---- layer 1 ----  (h lives in d_out; gemm2 consumes it before gather2 overwrites)
    gemm_kernel<<<gemm_grid, 256, 0, stream>>>(x, W1, b1, t, s_buf, N_NODES);
    gather_gn_kernel<<<gather_grid, 256, 0, stream>>>((const float4*)s_buf, rowptr, eid, gamma1, beta1, out, N_NODES);

    // ---- layer 2 ----
    gemm_kernel<<<gemm_grid, 256, 0, stream>>>(out, W2, b2, t, s_buf, N_NODES);
    gather_gn_kernel<<<gather_grid, 256, 0, stream>>>((const float4*)s_buf, rowptr, eid, gamma2, beta2, out, N_NODES);
}